// Round 7
// baseline (823.160 us; speedup 1.0000x reference)
//
#include <hip/hip_runtime.h>
#include <math.h>

// Problem constants
#define B_SZ 256
#define S_SZ 6
#define D_SZ 10000
#define DP   10112      // D padded to 158*64
#define C_SZ 128
#define K_SZ 500
#define KP   512        // codebook rows padded (8 k-tiles of 64)
#define NIT  (DP / 64)  // 158 K-iterations

typedef _Float16     half8  __attribute__((ext_vector_type(8)));
typedef float        f32x4  __attribute__((ext_vector_type(4)));
typedef unsigned int u32x4v __attribute__((ext_vector_type(4)));

__device__ __forceinline__ void stage16(const void* g, void* l) {
    __builtin_amdgcn_global_load_lds(
        (const __attribute__((address_space(1))) unsigned int*)g,
        (__attribute__((address_space(3))) unsigned int*)l, 16, 0, 0);
}

// ---- prep: W_reg (fp32) -> f16 hi, zero-padded [128][DP] ----
__global__ void prep_whi(const float* __restrict__ wreg, _Float16* __restrict__ whi) {
    int t = blockIdx.x * 256 + threadIdx.x;
    if (t >= C_SZ * DP) return;
    int c = t / DP, d = t - c * DP;
    float w = (d < D_SZ) ? wreg[c * D_SZ + d] : 0.0f;
    whi[t] = (_Float16)w;
}

// ---- prep: rigorous per-class L1 bound err[c] = sum_d |w - f16(w)| (+ slack) ----
__global__ void prep_err(const float* __restrict__ wreg, float* __restrict__ err) {
    __shared__ float red[256];
    int c = blockIdx.x, tid = threadIdx.x;
    float p = 0.0f;
    for (int d = tid; d < D_SZ; d += 256) {
        float w = wreg[c * D_SZ + d];
        p += fabsf(w - (float)(_Float16)w);
    }
    red[tid] = p; __syncthreads();
    for (int s = 128; s > 0; s >>= 1) { if (tid < s) red[tid] += red[tid + s]; __syncthreads(); }
    if (tid == 0) err[c] = red[0] * 1.01f + 0.05f;  // fp32-sum slack + MFMA-accum slack
}

// ---- prep: codebook (±1 fp32) -> f16, zero-padded to [512][DP] ----
__global__ void prep_cb(const float* __restrict__ cb, _Float16* __restrict__ cbp) {
    int t = blockIdx.x * 256 + threadIdx.x;
    if (t >= KP * DP) return;
    int k = t / DP, d = t - k * DP;
    float v = (k < K_SZ && d < D_SZ) ? cb[k * D_SZ + d] : 0.0f;
    cbp[t] = (_Float16)v;
}

// ---- prep: enc sign mask (0x0000 = +1, 0x8000 = -1), fp64 for exact sign match ----
__global__ void prep_enc(const float* __restrict__ x, const float* __restrict__ wp,
                         const float* __restrict__ bp, unsigned short* __restrict__ em) {
    int t = blockIdx.x * 256 + threadIdx.x;
    if (t >= B_SZ * DP) return;
    int b = t / DP, d = t - b * DP;
    unsigned short m = 0;
    if (d < D_SZ) {
        double p = 0.0;
        #pragma unroll
        for (int s = 0; s < S_SZ; ++s)
            p += (double)x[b * S_SZ + s] * (double)wp[d * S_SZ + s];
        double hv = cos(p + (double)bp[d]) * sin(p);
        m = (hv > 0.0) ? (unsigned short)0u : (unsigned short)0x8000u;
    }
    em[t] = m;
}

// ---- main: hi-only GEMM. block = 256 thr = 4 waves; tile 8b x 64c x 64k.
// Each wave: 2 batches x 64c x 64k -> 128 acc regs, 20 b128 LDS reads per
// 64 MFMA = 0.3125 reads/MFMA < 0.4 CU balance point -> MFMA-bound.
// Signs XORed onto B (cb) fragments. No dynamic acc indexing anywhere (R4 lesson).
// LDS XOR-swizzled: 16-B chunk p of row r holds logical chunk (p^(r&7)) -> 0 conflicts.
// Writes full sim_hi tile as f16 (scan+refine certify/fix the argmax afterwards).
__global__ __launch_bounds__(256) void gemm_hi(
    const _Float16* __restrict__ whi, const _Float16* __restrict__ cbp,
    const unsigned short* __restrict__ em, _Float16* __restrict__ simh)
{
    const int kt = blockIdx.x >> 1;   // 0..7  k-tile (64 codebook rows)
    const int ct = blockIdx.x & 1;    // 0..1  c-tile (64 classes)
    const int bg = blockIdx.y;        // 0..31 batch group (8 batches)
    const int tid  = threadIdx.x;
    const int wave = tid >> 6;
    const int lane = tid & 63;
    const int quad = lane >> 4;
    const int col  = lane & 15;

    __shared__ __align__(16) _Float16 s_whi[64 * 64];
    __shared__ __align__(16) _Float16 s_cb [64 * 64];
    __shared__ __align__(16) unsigned short s_mask[8 * 64];

    f32x4 acc[2][4][4];
    #pragma unroll
    for (int b = 0; b < 2; ++b)
        #pragma unroll
        for (int m = 0; m < 4; ++m)
            #pragma unroll
            for (int n = 0; n < 4; ++n)
                acc[b][m][n] = (f32x4){0.f, 0.f, 0.f, 0.f};

    const int c0  = ct * 64;
    const int kr0 = kt * 64;
    const int b0  = bg * 8;

    // staging geometry: slot e: row=e>>3, pos p=e&7; global chunk = p^(row&7)
    size_t aoff[2], boff[2];
    int soff[2];
    #pragma unroll
    for (int s = 0; s < 2; ++s) {
        int e = s * 256 + tid;          // 0..511
        int row = e >> 3;
        int p = e & 7;
        int gcol = (p ^ (row & 7)) * 8;
        aoff[s] = (size_t)(c0 + row) * DP + gcol;
        boff[s] = (size_t)(kr0 + row) * DP + gcol;
        soff[s] = e * 8;
    }
    // mask staging (wave 0 only): 8 b x 64 ushorts = 1 KB, linear lane order
    const size_t moff = (size_t)(b0 + (lane >> 3)) * DP + (lane & 7) * 8;

    // LDS fragment row bases (f16 units)
    const int ar0 = (col) * 64, ar1 = (16 + col) * 64, ar2 = (32 + col) * 64, ar3 = (48 + col) * 64;

    for (int kb = 0; kb < NIT; ++kb) {
        const int k0 = kb * 64;
        stage16(whi + aoff[0] + k0, s_whi + soff[0]);
        stage16(whi + aoff[1] + k0, s_whi + soff[1]);
        stage16(cbp + boff[0] + k0, s_cb + soff[0]);
        stage16(cbp + boff[1] + k0, s_cb + soff[1]);
        if (wave == 0) stage16(em + moff + k0, s_mask + lane * 8);
        __syncthreads();

        #pragma unroll
        for (int k2 = 0; k2 < 2; ++k2) {
            const int chunk = k2 * 4 + quad;
            const int sw    = (chunk ^ (col & 7)) * 8;
            const half8 a0 = *(const half8*)(s_whi + ar0 + sw);
            const half8 a1 = *(const half8*)(s_whi + ar1 + sw);
            const half8 a2 = *(const half8*)(s_whi + ar2 + sw);
            const half8 a3 = *(const half8*)(s_whi + ar3 + sw);
            const u32x4v b0f = *(const u32x4v*)(s_cb + ar0 + sw);
            const u32x4v b1f = *(const u32x4v*)(s_cb + ar1 + sw);
            const u32x4v b2f = *(const u32x4v*)(s_cb + ar2 + sw);
            const u32x4v b3f = *(const u32x4v*)(s_cb + ar3 + sw);
            #pragma unroll
            for (int b = 0; b < 2; ++b) {
                const u32x4v mr = *(const u32x4v*)(s_mask + (wave * 2 + b) * 64 + chunk * 8);
                const half8 bs0 = __builtin_bit_cast(half8, b0f ^ mr);
                const half8 bs1 = __builtin_bit_cast(half8, b1f ^ mr);
                const half8 bs2 = __builtin_bit_cast(half8, b2f ^ mr);
                const half8 bs3 = __builtin_bit_cast(half8, b3f ^ mr);
                #pragma unroll
                for (int m = 0; m < 4; ++m) {
                    const half8 af = (m == 0) ? a0 : (m == 1) ? a1 : (m == 2) ? a2 : a3;
                    acc[b][m][0] = __builtin_amdgcn_mfma_f32_16x16x32_f16(af, bs0, acc[b][m][0], 0, 0, 0);
                    acc[b][m][1] = __builtin_amdgcn_mfma_f32_16x16x32_f16(af, bs1, acc[b][m][1], 0, 0, 0);
                    acc[b][m][2] = __builtin_amdgcn_mfma_f32_16x16x32_f16(af, bs2, acc[b][m][2], 0, 0, 0);
                    acc[b][m][3] = __builtin_amdgcn_mfma_f32_16x16x32_f16(af, bs3, acc[b][m][3], 0, 0, 0);
                }
            }
        }
        __syncthreads();
    }

    // ---- epilogue: store sim_hi as f16. C/D layout: col=lane&15 (k), row=quad*4+reg (c)
    #pragma unroll
    for (int b = 0; b < 2; ++b) {
        const size_t bb = (size_t)(b0 + wave * 2 + b) * 128;
        #pragma unroll
        for (int m = 0; m < 4; ++m)
            #pragma unroll
            for (int n = 0; n < 4; ++n)
                #pragma unroll
                for (int r = 0; r < 4; ++r) {
                    int cg = c0 + m * 16 + quad * 4 + r;
                    int kg = kr0 + n * 16 + col;
                    simh[(bb + cg) * 512 + kg] = (_Float16)acc[b][m][n][r];
                }
    }
}

// ---- scan: per (b,c) row of sim_hi: first-max, margin test, provisional pred ----
// One wave per row. If >1 candidate within M -> push row to refine queue.
__global__ __launch_bounds__(256) void scan_argmax(
    const _Float16* __restrict__ simh, const float* __restrict__ err,
    float* __restrict__ out, int* __restrict__ qcnt, int* __restrict__ queue)
{
    const int wave = threadIdx.x >> 6, lane = threadIdx.x & 63;
    const int row = blockIdx.x * 4 + wave;       // 0..32767
    const int c = row & 127;
    const half8 v8 = *(const half8*)(simh + (size_t)row * 512 + lane * 8);
    float bv = -3.0e38f; int bk = 0x7fffffff;
    #pragma unroll
    for (int j = 0; j < 8; ++j) {
        int k = lane * 8 + j;
        float v = (k < K_SZ) ? (float)v8[j] : -3.0e38f;
        if (v > bv) { bv = v; bk = k; }
    }
    #pragma unroll
    for (int off = 1; off < 64; off <<= 1) {
        float ov = __shfl_xor(bv, off, 64);
        int   ok = __shfl_xor(bk, off, 64);
        if (ov > bv || (ov == bv && ok < bk)) { bv = ov; bk = ok; }
    }
    const float M = 2.0f * err[c] + fabsf(bv) * 0.002f + 1.0f;  // covers hi-quant + accum + f16-store
    const float thr = bv - M;
    int cnt = 0;
    #pragma unroll
    for (int j = 0; j < 8; ++j) {
        int k = lane * 8 + j;
        float v = (k < K_SZ) ? (float)v8[j] : -3.0e38f;
        cnt += (v >= thr) ? 1 : 0;
    }
    #pragma unroll
    for (int off = 1; off < 64; off <<= 1) cnt += __shfl_xor(cnt, off, 64);
    if (lane == 0) {
        out[row] = (float)bk / 499.0f * 61.5f + (-19.9f);
        if (cnt > 1) { int qi = atomicAdd(qcnt, 1); queue[qi] = row; }
    }
}

// ---- refine: for flagged (b,c), fp64-exact sims for candidate k's; fix pred ----
__global__ __launch_bounds__(256) void refine(
    const float* __restrict__ wreg, const float* __restrict__ cb,
    const unsigned short* __restrict__ em, const _Float16* __restrict__ simh,
    const float* __restrict__ err, const int* __restrict__ qcnt,
    const int* __restrict__ queue, float* __restrict__ out)
{
    const int tid = threadIdx.x;
    const int nq = *qcnt;
    __shared__ float s_thr;
    __shared__ int s_cnt;
    __shared__ int s_list[512];
    __shared__ double s_red[256];

    for (int i = blockIdx.x; i < nq; i += gridDim.x) {
        const int row = queue[i];
        const int b = row >> 7, c = row & 127;
        const _Float16* sr = simh + (size_t)row * 512;
        if (tid < 64) {  // replicate scan's threshold computation (slack >> any fp drift)
            const half8 v8 = *(const half8*)(sr + tid * 8);
            float bv = -3.0e38f;
            #pragma unroll
            for (int j = 0; j < 8; ++j) {
                int k = tid * 8 + j;
                float v = (k < K_SZ) ? (float)v8[j] : -3.0e38f;
                if (v > bv) bv = v;
            }
            #pragma unroll
            for (int off = 1; off < 64; off <<= 1) {
                float ov = __shfl_xor(bv, off, 64);
                if (ov > bv) bv = ov;
            }
            if (tid == 0) {
                s_thr = bv - (2.0f * err[c] + fabsf(bv) * 0.002f + 1.0f);
                s_cnt = 0;
            }
        }
        __syncthreads();
        for (int k = tid; k < K_SZ; k += 256) {
            if ((float)sr[k] >= s_thr) { int p = atomicAdd(&s_cnt, 1); s_list[p] = k; }
        }
        __syncthreads();
        const int nc = s_cnt;
        double bestv = -1.0e300; int bestk = 0x7fffffff;
        for (int ci = 0; ci < nc; ++ci) {
            const int k = s_list[ci];
            double p = 0.0;
            for (int d = tid; d < D_SZ; d += 256) {
                double t = (double)wreg[c * D_SZ + d] * (double)cb[(size_t)k * D_SZ + d];
                p += em[(size_t)b * DP + d] ? -t : t;
            }
            s_red[tid] = p; __syncthreads();
            for (int st = 128; st > 0; st >>= 1) { if (tid < st) s_red[tid] += s_red[tid + st]; __syncthreads(); }
            if (tid == 0) {
                double sv = s_red[0];
                if (sv > bestv || (sv == bestv && k < bestk)) { bestv = sv; bestk = k; }
            }
            __syncthreads();
        }
        if (tid == 0) out[row] = (float)bestk / 499.0f * 61.5f + (-19.9f);
        __syncthreads();
    }
}

extern "C" void kernel_launch(void* const* d_in, const int* in_sizes, int n_in,
                              void* d_out, int out_size, void* d_ws, size_t ws_size,
                              hipStream_t stream) {
    const float* x    = (const float*)d_in[0];
    const float* wp   = (const float*)d_in[1];
    const float* bp   = (const float*)d_in[2];
    const float* wreg = (const float*)d_in[3];
    const float* cb   = (const float*)d_in[4];
    float* out = (float*)d_out;

    char* ws = (char*)d_ws;
    size_t o = 0;
    auto take = [&](size_t bytes) -> char* {
        o = (o + 255) & ~(size_t)255;
        char* p = ws + o;
        o += bytes;
        return p;
    };
    _Float16* whi       = (_Float16*)take(sizeof(_Float16) * C_SZ * DP);
    _Float16* cbp       = (_Float16*)take(sizeof(_Float16) * KP * DP);
    unsigned short* em  = (unsigned short*)take(sizeof(unsigned short) * B_SZ * DP);
    float* err          = (float*)take(sizeof(float) * C_SZ);
    _Float16* simh      = (_Float16*)take(sizeof(_Float16) * B_SZ * C_SZ * 512);
    int* qcnt           = (int*)take(sizeof(int));
    int* queue          = (int*)take(sizeof(int) * B_SZ * C_SZ);
    (void)ws_size; (void)in_sizes; (void)n_in; (void)out_size;

    prep_whi<<<(C_SZ * DP + 255) / 256, 256, 0, stream>>>(wreg, whi);
    prep_err<<<C_SZ, 256, 0, stream>>>(wreg, err);
    prep_cb<<<(KP * DP + 255) / 256, 256, 0, stream>>>(cb, cbp);
    prep_enc<<<(B_SZ * DP + 255) / 256, 256, 0, stream>>>(x, wp, bp, em);
    hipMemsetAsync(qcnt, 0, sizeof(int), stream);

    dim3 g(16, 32);  // x: kt*2+ct, y: batch group (8 b)
    gemm_hi<<<g, 256, 0, stream>>>(whi, cbp, em, simh);

    scan_argmax<<<(B_SZ * C_SZ) / 4, 256, 0, stream>>>(simh, err, out, qcnt, queue);
    refine<<<1024, 256, 0, stream>>>(wreg, cb, em, simh, err, qcnt, queue, out);
}